// Round 10
// baseline (692.480 us; speedup 1.0000x reference)
//
#include <hip/hip_runtime.h>
#include <hip/hip_bf16.h>
#include <math.h>

typedef __attribute__((ext_vector_type(8))) short short8;
typedef __attribute__((ext_vector_type(4))) float f32x4;

__device__ __forceinline__ float bf2f(unsigned short u) {
    union { unsigned int i; float f; } c; c.i = ((unsigned int)u) << 16; return c.f;
}
__device__ __forceinline__ unsigned short f2bf(float f) {
    union { float f; unsigned int i; } c; c.f = f;
    unsigned int i = c.i;
    unsigned int r = (i + 0x7FFFu + ((i >> 16) & 1u)) >> 16;
    return (unsigned short)r;
}
__device__ __forceinline__ float fexp2(float x) { return __builtin_amdgcn_exp2f(x); }

// vectorized 8-wide helpers for epilogue readback
__device__ __forceinline__ void load8(const unsigned short* p, float* v) {
    short8 s = *(const short8*)p;
#pragma unroll
    for (int i = 0; i < 8; i++) v[i] = bf2f((unsigned short)s[i]);
}
__device__ __forceinline__ void load8(const float* p, float* v) {
    f32x4 a = ((const f32x4*)p)[0], b = ((const f32x4*)p)[1];
    v[0] = a[0]; v[1] = a[1]; v[2] = a[2]; v[3] = a[3];
    v[4] = b[0]; v[5] = b[1]; v[6] = b[2]; v[7] = b[3];
}
__device__ __forceinline__ void store8(unsigned short* p, const float* v) {
    short8 s;
#pragma unroll
    for (int i = 0; i < 8; i++) s[i] = (short)f2bf(v[i]);
    *(short8*)p = s;
}
__device__ __forceinline__ void store8(float* p, const float* v) {
    f32x4 a, b;
    a[0] = v[0]; a[1] = v[1]; a[2] = v[2]; a[3] = v[3];
    b[0] = v[4]; b[1] = v[5]; b[2] = v[6]; b[7 - 4] = v[7];
    ((f32x4*)p)[0] = a; ((f32x4*)p)[1] = b;
}

// ---------------- LayerNorm (fp32 input) -> bf16 output ----------------
__global__ __launch_bounds__(256) void ln_f32_kernel(
    const float* __restrict__ x, const float* __restrict__ g,
    const float* __restrict__ b, unsigned short* __restrict__ out) {
    const int row = blockIdx.x;
    const int t = threadIdx.x;
    const float* xr = x + (size_t)row * 1024;
    float4 raw = ((const float4*)xr)[t];
    float v0 = raw.x, v1 = raw.y, v2 = raw.z, v3 = raw.w;
    float s = v0 + v1 + v2 + v3;
    float ss = v0 * v0 + v1 * v1 + v2 * v2 + v3 * v3;
    for (int off = 32; off > 0; off >>= 1) {
        s += __shfl_down(s, off);
        ss += __shfl_down(ss, off);
    }
    __shared__ float red[8];
    __shared__ float stat[2];
    const int wave = t >> 6, lane = t & 63;
    if (lane == 0) { red[wave] = s; red[4 + wave] = ss; }
    __syncthreads();
    if (t == 0) {
        float st = red[0] + red[1] + red[2] + red[3];
        float sst = red[4] + red[5] + red[6] + red[7];
        float mu = st * (1.0f / 1024.0f);
        float var = sst * (1.0f / 1024.0f) - mu * mu;
        stat[0] = mu; stat[1] = rsqrtf(var + 1e-5f);
    }
    __syncthreads();
    const float mu = stat[0], rstd = stat[1];
    float4 gr = ((const float4*)g)[t];
    float4 br = ((const float4*)b)[t];
    ushort4 o;
    o.x = f2bf((v0 - mu) * rstd * gr.x + br.x);
    o.y = f2bf((v1 - mu) * rstd * gr.y + br.y);
    o.z = f2bf((v2 - mu) * rstd * gr.z + br.z);
    o.w = f2bf((v3 - mu) * rstd * gr.w + br.w);
    ((ushort4*)(out + (size_t)row * 1024))[t] = o;
}

// ---------------- LayerNorm (bf16 input) -> bf16 output ----------------
__global__ __launch_bounds__(256) void ln_bf16_kernel(
    const unsigned short* __restrict__ x, const float* __restrict__ g,
    const float* __restrict__ b, unsigned short* __restrict__ out) {
    const int row = blockIdx.x;
    const int t = threadIdx.x;
    const unsigned short* xr = x + (size_t)row * 1024;
    ushort4 raw = ((const ushort4*)xr)[t];
    float v0 = bf2f(raw.x), v1 = bf2f(raw.y), v2 = bf2f(raw.z), v3 = bf2f(raw.w);
    float s = v0 + v1 + v2 + v3;
    float ss = v0 * v0 + v1 * v1 + v2 * v2 + v3 * v3;
    for (int off = 32; off > 0; off >>= 1) {
        s += __shfl_down(s, off);
        ss += __shfl_down(ss, off);
    }
    __shared__ float red[8];
    __shared__ float stat[2];
    const int wave = t >> 6, lane = t & 63;
    if (lane == 0) { red[wave] = s; red[4 + wave] = ss; }
    __syncthreads();
    if (t == 0) {
        float st = red[0] + red[1] + red[2] + red[3];
        float sst = red[4] + red[5] + red[6] + red[7];
        float mu = st * (1.0f / 1024.0f);
        float var = sst * (1.0f / 1024.0f) - mu * mu;
        stat[0] = mu; stat[1] = rsqrtf(var + 1e-5f);
    }
    __syncthreads();
    const float mu = stat[0], rstd = stat[1];
    float4 gr = ((const float4*)g)[t];
    float4 br = ((const float4*)b)[t];
    ushort4 o;
    o.x = f2bf((v0 - mu) * rstd * gr.x + br.x);
    o.y = f2bf((v1 - mu) * rstd * gr.y + br.y);
    o.z = f2bf((v2 - mu) * rstd * gr.z + br.z);
    o.w = f2bf((v3 - mu) * rstd * gr.w + br.w);
    ((ushort4*)(out + (size_t)row * 1024))[t] = o;
}

// ---------------- Transpose+cast: fp32 in[R][C] -> bf16 out[C][R] ----------------
__global__ __launch_bounds__(256) void transpose_cast_kernel(
    const float* __restrict__ in, unsigned short* __restrict__ out, int R, int C) {
    __shared__ unsigned short tile[32][33];
    const int bx = blockIdx.x * 32, by = blockIdx.y * 32;
    const int tx = threadIdx.x & 31, ty = threadIdx.x >> 5;
    for (int i = 0; i < 32; i += 8)
        tile[ty + i][tx] = f2bf(in[(size_t)(by + ty + i) * C + bx + tx]);
    __syncthreads();
    for (int i = 0; i < 32; i += 8)
        out[(size_t)(bx + ty + i) * R + by + tx] = tile[tx][ty + i];
}

// ---------------- GEMM: C[M,N] = A[M,K] * Bt[N,K]^T + bias, fused epilogues ----
// (r0 best-measured version, unchanged.)
enum { EPI_QKV = 0, EPI_RES = 1, EPI_GELU = 2 };

template <int EPI, typename RT, typename OT>
__global__ __launch_bounds__(256) void gemm_bt(
    const unsigned short* __restrict__ A, const unsigned short* __restrict__ Bt,
    const float* __restrict__ bias, const RT* __restrict__ res,
    OT* __restrict__ o0, unsigned short* __restrict__ o1,
    unsigned short* __restrict__ o2, int M, int N, int K) {
    constexpr int LDW = 40;   // staging row pitch (shorts)
    constexpr int LE = 136;   // epilogue row pitch (shorts)
    __shared__ __align__(16) unsigned short SMEM[20480];  // 40 KB
    const int t = threadIdx.x;
    const int wave = t >> 6, lane = t & 63;
    const int lr = lane & 15, lq = lane >> 4;
    const int wm = (wave >> 1) * 64, wn = (wave & 1) * 64;
    const int m0 = blockIdx.y * 128, n0 = blockIdx.x * 128;
    f32x4 acc[4][4] = {};
    const int arow = t >> 2, acol = (t & 3) << 3;
    const unsigned short* ag = A + (size_t)(m0 + arow) * K + acol;
    const unsigned short* bg = Bt + (size_t)(n0 + arow) * K + acol;
    const size_t rstride = (size_t)64 * K;
    short8 a0 = *(const short8*)(ag);
    short8 a1 = *(const short8*)(ag + rstride);
    short8 b0 = *(const short8*)(bg);
    short8 b1 = *(const short8*)(bg + rstride);
    const int nit = K >> 5;
    for (int it = 0; it < nit; ++it) {
        const int buf = (it & 1) * 10240;  // double-buffer offset (no pointer table)
        unsigned short* As = SMEM + buf;
        unsigned short* Bs = SMEM + buf + 5120;
        *(short8*)(As + arow * LDW + acol) = a0;
        *(short8*)(As + (arow + 64) * LDW + acol) = a1;
        *(short8*)(Bs + arow * LDW + acol) = b0;
        *(short8*)(Bs + (arow + 64) * LDW + acol) = b1;
        if (it + 1 < nit) {  // full-iteration latency window
            const int k0 = (it + 1) << 5;
            a0 = *(const short8*)(ag + k0);
            a1 = *(const short8*)(ag + rstride + k0);
            b0 = *(const short8*)(bg + k0);
            b1 = *(const short8*)(bg + rstride + k0);
        }
        __syncthreads();
        short8 af[4], bfr[4];
#pragma unroll
        for (int i = 0; i < 4; i++) af[i] = *(const short8*)(As + (wm + i * 16 + lr) * LDW + lq * 8);
#pragma unroll
        for (int i = 0; i < 4; i++) bfr[i] = *(const short8*)(Bs + (wn + i * 16 + lr) * LDW + lq * 8);
#pragma unroll
        for (int mi = 0; mi < 4; mi++)
#pragma unroll
            for (int ni = 0; ni < 4; ni++)
                acc[mi][ni] = __builtin_amdgcn_mfma_f32_16x16x32_bf16(af[mi], bfr[ni], acc[mi][ni], 0, 0, 0);
    }
    // ---- epilogue: bias (+gelu) -> LDS stage -> coalesced writeback ----
    __syncthreads();  // staging buffers now free for reuse
    const bool vreg = (EPI == EPI_QKV) && (n0 >= 2048);
#pragma unroll
    for (int ni = 0; ni < 4; ni++) {
        const int col = wn + ni * 16 + lr;
        const float bv = bias[n0 + col];
#pragma unroll
        for (int mi = 0; mi < 4; mi++) {
#pragma unroll
            for (int r = 0; r < 4; r++) {
                const int row = wm + mi * 16 + lq * 4 + r;
                float val = acc[mi][ni][r] + bv;
                if (EPI == EPI_GELU)
                    val = 0.5f * val * (1.0f + erff(val * 0.70710678118654752f));
                if (vreg) SMEM[col * LE + row] = f2bf(val);
                else      SMEM[row * LE + col] = f2bf(val);
            }
        }
    }
    __syncthreads();
    const int rr = t >> 1, half = (t & 1) * 64;
    if (EPI == EPI_RES || EPI == EPI_GELU) {
        const size_t base = (size_t)(m0 + rr) * N + n0 + half;
        const unsigned short* src = SMEM + rr * LE + half;
#pragma unroll
        for (int j = 0; j < 8; j++) {
            float v[8];
            load8(src + j * 8, v);
            if (EPI == EPI_RES) {
                float rv[8];
                load8(res + base + j * 8, rv);
#pragma unroll
                for (int i = 0; i < 8; i++) v[i] += rv[i];
            }
            store8(o0 + base + j * 8, v);
        }
    } else if (!vreg) {  // q/k: out[(bh*2048+s)*64 + d]
        const int gcol0 = n0 + half;
        const int which = gcol0 >> 10;          // 0=q, 1=k (uniform per block half)
        const int hn = (gcol0 & 1023) >> 6;
        const int grow = m0 + rr;
        const size_t bh = (size_t)((grow >> 11) * 16 + hn);
        unsigned short* dst = (which == 0) ? (unsigned short*)o0 : o1;
        dst += (bh * 2048 + (grow & 2047)) * 64;
        const unsigned short* src = SMEM + rr * LE + half;
#pragma unroll
        for (int j = 0; j < 8; j++)
            *(short8*)(dst + j * 8) = *(const short8*)(src + j * 8);
    } else {  // v^T: out[(bh*64+d)*2048 + s], staged transposed
        const int c = rr;
        const int rem = (n0 + c) - 2048;
        const int hn = rem >> 6, d = rem & 63;
        const size_t bh = (size_t)((m0 >> 11) * 16 + hn);
        unsigned short* dst = o2 + (bh * 64 + d) * 2048 + (m0 & 2047) + half;
        const unsigned short* src = SMEM + c * LE + half;
#pragma unroll
        for (int j = 0; j < 8; j++)
            *(short8*)(dst + j * 8) = *(const short8*)(src + j * 8);
    }
}

// ---------------- Flash attention v3, causal. Hd=64, S=2048, BH=64 ----------------
// r10: r9 structure (256-row Q-tile, 8 waves, paired (q,7-q), 256 uniform
// blocks) + DOUBLE-BUFFERED K/V LDS -> ONE barrier per K-tile (was 2).
// Safety: a wave's ds_reads of buf are lgkm-retired before it issues the next
// store; the store into buf[kt&1] at iter kt+2 is gated by sync(kt+1), which
// every wave passes only after its compute-kt reads retired. Phase-start sync
// protects the cross-phase buffer handoff. setprio(1) around MFMA clusters
// (T5: +4-7% attn, m191). LDS 69.6 KB.
__global__ __launch_bounds__(512) void attn_kernel(
    const unsigned short* __restrict__ qb, const unsigned short* __restrict__ kb,
    const unsigned short* __restrict__ vtb, unsigned short* __restrict__ aout) {
    const int bx = blockIdx.x;  // 0..3
    const int bh = blockIdx.y;
    const int bidx = bh >> 4, h = bh & 15;
    const int t = threadIdx.x, wave = t >> 6, lane = t & 63;
    const int lr = lane & 15, lq = lane >> 4;
    __shared__ __align__(16) unsigned short Ks[2][64 * 68];
    __shared__ __align__(16) unsigned short Vs[2][64 * 68];
    __shared__ __align__(16) unsigned short Ps[8][32 * 68];
    const unsigned short* kbase = kb + (size_t)bh * 2048 * 64;
    const unsigned short* vbase = vtb + (size_t)bh * 64 * 2048;
    const int srow = t >> 3, scol = (t & 7) * 8;  // 512 threads -> rows 0..63
    const float kQScale = 0.125f * 1.44269504088896f;

    for (int phase = 0; phase < 2; phase++) {
        const int qblk = phase ? (7 - bx) : bx;
        const unsigned short* qbase = qb + ((size_t)bh * 2048 + qblk * 256 + wave * 32) * 64;
        short8 qf[2][2];
#pragma unroll
        for (int f = 0; f < 2; f++)
#pragma unroll
            for (int c = 0; c < 2; c++) {
                short8 raw = *(const short8*)(qbase + (f * 16 + lr) * 64 + c * 32 + lq * 8);
                short8 sc;
#pragma unroll
                for (int j = 0; j < 8; j++)
                    sc[j] = (short)f2bf(bf2f((unsigned short)raw[j]) * kQScale);
                qf[f][c] = sc;
            }
        f32x4 acc[2][4] = {};
        float m_i[2][4], l_i[2][4];
#pragma unroll
        for (int f = 0; f < 2; f++)
#pragma unroll
            for (int r = 0; r < 4; r++) { m_i[f][r] = -1e30f; l_i[f][r] = 0.0f; }
        const int wave_q0 = qblk * 256 + wave * 32;
        const int nkt = 4 * (qblk + 1);
        short8 kr = *(const short8*)(kbase + t * 8);
        short8 vr = *(const short8*)(vbase + (size_t)srow * 2048 + scol);
        __syncthreads();  // phase handoff: prior phase's LDS reads all retired
        for (int kt = 0; kt < nkt; kt++) {
            unsigned short* Kb = Ks[kt & 1];
            unsigned short* Vb = Vs[kt & 1];
            *(short8*)(Kb + srow * 68 + scol) = kr;
            *(short8*)(Vb + srow * 68 + scol) = vr;
            __syncthreads();  // single barrier per K-tile (double-buffered)
            if (kt + 1 < nkt) {
                kr = *(const short8*)(kbase + (size_t)(kt + 1) * 4096 + t * 8);
                vr = *(const short8*)(vbase + (size_t)srow * 2048 + (kt + 1) * 64 + scol);
            }
            if (kt * 64 <= wave_q0 + 31) {
                f32x4 sa[2][4];
                __builtin_amdgcn_s_setprio(1);
#pragma unroll
                for (int ni = 0; ni < 4; ni++) {
                    short8 kf0 = *(const short8*)(Kb + (ni * 16 + lr) * 68 + lq * 8);
                    short8 kf1 = *(const short8*)(Kb + (ni * 16 + lr) * 68 + 32 + lq * 8);
#pragma unroll
                    for (int f = 0; f < 2; f++) {
                        f32x4 z = {};
                        z = __builtin_amdgcn_mfma_f32_16x16x32_bf16(qf[f][0], kf0, z, 0, 0, 0);
                        sa[f][ni] = __builtin_amdgcn_mfma_f32_16x16x32_bf16(qf[f][1], kf1, z, 0, 0, 0);
                    }
                }
                __builtin_amdgcn_s_setprio(0);
                const bool needmask = (kt * 64 + 63 > wave_q0);
                if (needmask) {
#pragma unroll
                    for (int f = 0; f < 2; f++) {
                        const int qrow0 = wave_q0 + f * 16 + lq * 4;
#pragma unroll
                        for (int ni = 0; ni < 4; ni++) {
                            const int kcol = kt * 64 + ni * 16 + lr;
#pragma unroll
                            for (int r = 0; r < 4; r++)
                                if (kcol > qrow0 + r) sa[f][ni][r] = -1e30f;
                        }
                    }
                }
#pragma unroll
                for (int f = 0; f < 2; f++) {
                    float mcur[4], alpha[4], rsum[4];
#pragma unroll
                    for (int r = 0; r < 4; r++)
                        mcur[r] = fmaxf(fmaxf(sa[f][0][r], sa[f][1][r]), fmaxf(sa[f][2][r], sa[f][3][r]));
#pragma unroll
                    for (int r = 0; r < 4; r++) {
#pragma unroll
                        for (int off = 1; off < 16; off <<= 1) mcur[r] = fmaxf(mcur[r], __shfl_xor(mcur[r], off));
                        const float mn = fmaxf(m_i[f][r], mcur[r]);
                        alpha[r] = fexp2(m_i[f][r] - mn);
                        m_i[f][r] = mn;
                        rsum[r] = 0.0f;
                    }
#pragma unroll
                    for (int ni = 0; ni < 4; ni++)
#pragma unroll
                        for (int r = 0; r < 4; r++) {
                            const float p = fexp2(sa[f][ni][r] - m_i[f][r]);
                            Ps[wave][(f * 16 + lq * 4 + r) * 68 + ni * 16 + lr] = f2bf(p);
                            rsum[r] += p;
                        }
#pragma unroll
                    for (int r = 0; r < 4; r++) {
#pragma unroll
                        for (int off = 1; off < 16; off <<= 1) rsum[r] += __shfl_xor(rsum[r], off);
                        l_i[f][r] = l_i[f][r] * alpha[r] + rsum[r];
#pragma unroll
                        for (int ni = 0; ni < 4; ni++) acc[f][ni][r] *= alpha[r];
                    }
                }
                short8 pf[2][2];
#pragma unroll
                for (int f = 0; f < 2; f++)
#pragma unroll
                    for (int c = 0; c < 2; c++)
                        pf[f][c] = *(const short8*)(&Ps[wave][(f * 16 + lr) * 68 + c * 32 + lq * 8]);
                __builtin_amdgcn_s_setprio(1);
#pragma unroll
                for (int ni = 0; ni < 4; ni++) {
                    short8 vf0 = *(const short8*)(Vb + (ni * 16 + lr) * 68 + lq * 8);
                    short8 vf1 = *(const short8*)(Vb + (ni * 16 + lr) * 68 + 32 + lq * 8);
#pragma unroll
                    for (int f = 0; f < 2; f++) {
                        acc[f][ni] = __builtin_amdgcn_mfma_f32_16x16x32_bf16(pf[f][0], vf0, acc[f][ni], 0, 0, 0);
                        acc[f][ni] = __builtin_amdgcn_mfma_f32_16x16x32_bf16(pf[f][1], vf1, acc[f][ni], 0, 0, 0);
                    }
                }
                __builtin_amdgcn_s_setprio(0);
            }
        }
#pragma unroll
        for (int f = 0; f < 2; f++)
#pragma unroll
            for (int r = 0; r < 4; r++) {
                const float rinv = 1.0f / l_i[f][r];
                const int q = qblk * 256 + wave * 32 + f * 16 + lq * 4 + r;
                const size_t token = (size_t)bidx * 2048 + q;
#pragma unroll
                for (int ni = 0; ni < 4; ni++)
                    aout[token * 1024 + h * 64 + ni * 16 + lr] = f2bf(acc[f][ni][r] * rinv);
            }
    }
}

// ---------------- launch ----------------
extern "C" void kernel_launch(void* const* d_in, const int* in_sizes, int n_in,
                              void* d_out, int out_size, void* d_ws, size_t ws_size,
                              hipStream_t stream) {
    const float* x      = (const float*)d_in[0];
    const float* qkv_w  = (const float*)d_in[1];
    const float* qkv_b  = (const float*)d_in[2];
    const float* out_w  = (const float*)d_in[3];
    const float* out_b  = (const float*)d_in[4];
    const float* ffn1_w = (const float*)d_in[5];
    const float* ffn1_b = (const float*)d_in[6];
    const float* ffn2_w = (const float*)d_in[7];
    const float* ffn2_b = (const float*)d_in[8];
    const float* ln1_g  = (const float*)d_in[9];
    const float* ln1_b  = (const float*)d_in[10];
    const float* ln2_g  = (const float*)d_in[11];
    const float* ln2_b  = (const float*)d_in[12];
    float* out = (float*)d_out;
    char* W = (char*)d_ws;

    unsigned short* normed = (unsigned short*)(W);
    unsigned short* x1     = (unsigned short*)(W + 16777216);
    unsigned short* qbuf   = (unsigned short*)(W + 33554432);
    unsigned short* kbuf   = (unsigned short*)(W + 50331648);
    unsigned short* vbuf   = (unsigned short*)(W + 67108864);
    unsigned short* attnb  = (unsigned short*)(W + 83886080);
    unsigned short* hff    = (unsigned short*)(W + 33554432);  // reuses q/k/v/attn (dead)
    unsigned short* qkv_wt = (unsigned short*)(W + 100663296);
    unsigned short* out_wt = (unsigned short*)(W + 106954752);
    unsigned short* f1_wt  = (unsigned short*)(W + 109051904);
    unsigned short* f2_wt  = (unsigned short*)(W + 117440512);

    transpose_cast_kernel<<<dim3(3072 / 32, 1024 / 32), 256, 0, stream>>>(qkv_w, qkv_wt, 1024, 3072);
    transpose_cast_kernel<<<dim3(1024 / 32, 1024 / 32), 256, 0, stream>>>(out_w, out_wt, 1024, 1024);
    transpose_cast_kernel<<<dim3(4096 / 32, 1024 / 32), 256, 0, stream>>>(ffn1_w, f1_wt, 1024, 4096);
    transpose_cast_kernel<<<dim3(1024 / 32, 4096 / 32), 256, 0, stream>>>(ffn2_w, f2_wt, 4096, 1024);

    ln_f32_kernel<<<dim3(8192), 256, 0, stream>>>(x, ln1_g, ln1_b, normed);
    gemm_bt<EPI_QKV, float, unsigned short><<<dim3(3072 / 128, 8192 / 128), 256, 0, stream>>>(
        normed, qkv_wt, qkv_b, nullptr, qbuf, kbuf, vbuf, 8192, 3072, 1024);
    attn_kernel<<<dim3(4, 64), 512, 0, stream>>>(qbuf, kbuf, vbuf, attnb);
    gemm_bt<EPI_RES, float, unsigned short><<<dim3(1024 / 128, 8192 / 128), 256, 0, stream>>>(
        attnb, out_wt, out_b, x, x1, nullptr, nullptr, 8192, 1024, 1024);
    ln_bf16_kernel<<<dim3(8192), 256, 0, stream>>>(x1, ln2_g, ln2_b, normed);
    gemm_bt<EPI_GELU, float, unsigned short><<<dim3(4096 / 128, 8192 / 128), 256, 0, stream>>>(
        normed, f1_wt, ffn1_b, nullptr, hff, nullptr, nullptr, 8192, 4096, 1024);
    gemm_bt<EPI_RES, unsigned short, float><<<dim3(1024 / 128, 8192 / 128), 256, 0, stream>>>(
        hff, f2_wt, ffn2_b, x1, out, nullptr, nullptr, 8192, 1024, 4096);
}

// Round 11
// 598.296 us; speedup vs baseline: 1.1574x; 1.1574x over previous
//
#include <hip/hip_runtime.h>
#include <hip/hip_bf16.h>
#include <math.h>

typedef __attribute__((ext_vector_type(8))) short short8;
typedef __attribute__((ext_vector_type(4))) float f32x4;

__device__ __forceinline__ float bf2f(unsigned short u) {
    union { unsigned int i; float f; } c; c.i = ((unsigned int)u) << 16; return c.f;
}
__device__ __forceinline__ unsigned short f2bf(float f) {
    union { float f; unsigned int i; } c; c.f = f;
    unsigned int i = c.i;
    unsigned int r = (i + 0x7FFFu + ((i >> 16) & 1u)) >> 16;
    return (unsigned short)r;
}
__device__ __forceinline__ float fexp2(float x) { return __builtin_amdgcn_exp2f(x); }

// async global->LDS, 16B per lane. dst must be lane-linear (base + lane*16).
__device__ __forceinline__ void gload16(const unsigned short* g, unsigned short* l) {
    __builtin_amdgcn_global_load_lds(
        (const __attribute__((address_space(1))) unsigned int*)g,
        (__attribute__((address_space(3))) unsigned int*)l, 16, 0, 0);
}

// vectorized 8-wide helpers for epilogue readback
__device__ __forceinline__ void load8(const unsigned short* p, float* v) {
    short8 s = *(const short8*)p;
#pragma unroll
    for (int i = 0; i < 8; i++) v[i] = bf2f((unsigned short)s[i]);
}
__device__ __forceinline__ void load8(const float* p, float* v) {
    f32x4 a = ((const f32x4*)p)[0], b = ((const f32x4*)p)[1];
    v[0] = a[0]; v[1] = a[1]; v[2] = a[2]; v[3] = a[3];
    v[4] = b[0]; v[5] = b[1]; v[6] = b[2]; v[7] = b[3];
}
__device__ __forceinline__ void store8(unsigned short* p, const float* v) {
    short8 s;
#pragma unroll
    for (int i = 0; i < 8; i++) s[i] = (short)f2bf(v[i]);
    *(short8*)p = s;
}
__device__ __forceinline__ void store8(float* p, const float* v) {
    f32x4 a, b;
    a[0] = v[0]; a[1] = v[1]; a[2] = v[2]; a[3] = v[3];
    b[0] = v[4]; b[1] = v[5]; b[2] = v[6]; b[3] = v[7];
    ((f32x4*)p)[0] = a; ((f32x4*)p)[1] = b;
}

// ---------------- LayerNorm (fp32 input) -> bf16 output ----------------
__global__ __launch_bounds__(256) void ln_f32_kernel(
    const float* __restrict__ x, const float* __restrict__ g,
    const float* __restrict__ b, unsigned short* __restrict__ out) {
    const int row = blockIdx.x;
    const int t = threadIdx.x;
    const float* xr = x + (size_t)row * 1024;
    float4 raw = ((const float4*)xr)[t];
    float v0 = raw.x, v1 = raw.y, v2 = raw.z, v3 = raw.w;
    float s = v0 + v1 + v2 + v3;
    float ss = v0 * v0 + v1 * v1 + v2 * v2 + v3 * v3;
    for (int off = 32; off > 0; off >>= 1) {
        s += __shfl_down(s, off);
        ss += __shfl_down(ss, off);
    }
    __shared__ float red[8];
    __shared__ float stat[2];
    const int wave = t >> 6, lane = t & 63;
    if (lane == 0) { red[wave] = s; red[4 + wave] = ss; }
    __syncthreads();
    if (t == 0) {
        float st = red[0] + red[1] + red[2] + red[3];
        float sst = red[4] + red[5] + red[6] + red[7];
        float mu = st * (1.0f / 1024.0f);
        float var = sst * (1.0f / 1024.0f) - mu * mu;
        stat[0] = mu; stat[1] = rsqrtf(var + 1e-5f);
    }
    __syncthreads();
    const float mu = stat[0], rstd = stat[1];
    float4 gr = ((const float4*)g)[t];
    float4 br = ((const float4*)b)[t];
    ushort4 o;
    o.x = f2bf((v0 - mu) * rstd * gr.x + br.x);
    o.y = f2bf((v1 - mu) * rstd * gr.y + br.y);
    o.z = f2bf((v2 - mu) * rstd * gr.z + br.z);
    o.w = f2bf((v3 - mu) * rstd * gr.w + br.w);
    ((ushort4*)(out + (size_t)row * 1024))[t] = o;
}

// ---------------- LayerNorm (bf16 input) -> bf16 output ----------------
__global__ __launch_bounds__(256) void ln_bf16_kernel(
    const unsigned short* __restrict__ x, const float* __restrict__ g,
    const float* __restrict__ b, unsigned short* __restrict__ out) {
    const int row = blockIdx.x;
    const int t = threadIdx.x;
    const unsigned short* xr = x + (size_t)row * 1024;
    ushort4 raw = ((const ushort4*)xr)[t];
    float v0 = bf2f(raw.x), v1 = bf2f(raw.y), v2 = bf2f(raw.z), v3 = bf2f(raw.w);
    float s = v0 + v1 + v2 + v3;
    float ss = v0 * v0 + v1 * v1 + v2 * v2 + v3 * v3;
    for (int off = 32; off > 0; off >>= 1) {
        s += __shfl_down(s, off);
        ss += __shfl_down(ss, off);
    }
    __shared__ float red[8];
    __shared__ float stat[2];
    const int wave = t >> 6, lane = t & 63;
    if (lane == 0) { red[wave] = s; red[4 + wave] = ss; }
    __syncthreads();
    if (t == 0) {
        float st = red[0] + red[1] + red[2] + red[3];
        float sst = red[4] + red[5] + red[6] + red[7];
        float mu = st * (1.0f / 1024.0f);
        float var = sst * (1.0f / 1024.0f) - mu * mu;
        stat[0] = mu; stat[1] = rsqrtf(var + 1e-5f);
    }
    __syncthreads();
    const float mu = stat[0], rstd = stat[1];
    float4 gr = ((const float4*)g)[t];
    float4 br = ((const float4*)b)[t];
    ushort4 o;
    o.x = f2bf((v0 - mu) * rstd * gr.x + br.x);
    o.y = f2bf((v1 - mu) * rstd * gr.y + br.y);
    o.z = f2bf((v2 - mu) * rstd * gr.z + br.z);
    o.w = f2bf((v3 - mu) * rstd * gr.w + br.w);
    ((ushort4*)(out + (size_t)row * 1024))[t] = o;
}

// ---------------- Transpose+cast: fp32 in[R][C] -> bf16 out[C][R] ----------------
__global__ __launch_bounds__(256) void transpose_cast_kernel(
    const float* __restrict__ in, unsigned short* __restrict__ out, int R, int C) {
    __shared__ unsigned short tile[32][33];
    const int bx = blockIdx.x * 32, by = blockIdx.y * 32;
    const int tx = threadIdx.x & 31, ty = threadIdx.x >> 5;
    for (int i = 0; i < 32; i += 8)
        tile[ty + i][tx] = f2bf(in[(size_t)(by + ty + i) * C + bx + tx]);
    __syncthreads();
    for (int i = 0; i < 32; i += 8)
        out[(size_t)(bx + ty + i) * R + by + tx] = tile[tx][ty + i];
}

// ---------------- GEMM (r0): 128x128 tile, reg-staged, for QKV + proj ----------
enum { EPI_QKV = 0, EPI_RES = 1, EPI_GELU = 2 };

template <int EPI, typename RT, typename OT>
__global__ __launch_bounds__(256) void gemm_bt(
    const unsigned short* __restrict__ A, const unsigned short* __restrict__ Bt,
    const float* __restrict__ bias, const RT* __restrict__ res,
    OT* __restrict__ o0, unsigned short* __restrict__ o1,
    unsigned short* __restrict__ o2, int M, int N, int K) {
    constexpr int LDW = 40;   // staging row pitch (shorts)
    constexpr int LE = 136;   // epilogue row pitch (shorts)
    __shared__ __align__(16) unsigned short SMEM[20480];  // 40 KB
    const int t = threadIdx.x;
    const int wave = t >> 6, lane = t & 63;
    const int lr = lane & 15, lq = lane >> 4;
    const int wm = (wave >> 1) * 64, wn = (wave & 1) * 64;
    const int m0 = blockIdx.y * 128, n0 = blockIdx.x * 128;
    f32x4 acc[4][4] = {};
    const int arow = t >> 2, acol = (t & 3) << 3;
    const unsigned short* ag = A + (size_t)(m0 + arow) * K + acol;
    const unsigned short* bg = Bt + (size_t)(n0 + arow) * K + acol;
    const size_t rstride = (size_t)64 * K;
    short8 a0 = *(const short8*)(ag);
    short8 a1 = *(const short8*)(ag + rstride);
    short8 b0 = *(const short8*)(bg);
    short8 b1 = *(const short8*)(bg + rstride);
    const int nit = K >> 5;
    for (int it = 0; it < nit; ++it) {
        const int buf = (it & 1) * 10240;
        unsigned short* As = SMEM + buf;
        unsigned short* Bs = SMEM + buf + 5120;
        *(short8*)(As + arow * LDW + acol) = a0;
        *(short8*)(As + (arow + 64) * LDW + acol) = a1;
        *(short8*)(Bs + arow * LDW + acol) = b0;
        *(short8*)(Bs + (arow + 64) * LDW + acol) = b1;
        if (it + 1 < nit) {
            const int k0 = (it + 1) << 5;
            a0 = *(const short8*)(ag + k0);
            a1 = *(const short8*)(ag + rstride + k0);
            b0 = *(const short8*)(bg + k0);
            b1 = *(const short8*)(bg + rstride + k0);
        }
        __syncthreads();
        short8 af[4], bfr[4];
#pragma unroll
        for (int i = 0; i < 4; i++) af[i] = *(const short8*)(As + (wm + i * 16 + lr) * LDW + lq * 8);
#pragma unroll
        for (int i = 0; i < 4; i++) bfr[i] = *(const short8*)(Bs + (wn + i * 16 + lr) * LDW + lq * 8);
#pragma unroll
        for (int mi = 0; mi < 4; mi++)
#pragma unroll
            for (int ni = 0; ni < 4; ni++)
                acc[mi][ni] = __builtin_amdgcn_mfma_f32_16x16x32_bf16(af[mi], bfr[ni], acc[mi][ni], 0, 0, 0);
    }
    __syncthreads();
    const bool vreg = (EPI == EPI_QKV) && (n0 >= 2048);
#pragma unroll
    for (int ni = 0; ni < 4; ni++) {
        const int col = wn + ni * 16 + lr;
        const float bv = bias[n0 + col];
#pragma unroll
        for (int mi = 0; mi < 4; mi++) {
#pragma unroll
            for (int r = 0; r < 4; r++) {
                const int row = wm + mi * 16 + lq * 4 + r;
                float val = acc[mi][ni][r] + bv;
                if (EPI == EPI_GELU)
                    val = 0.5f * val * (1.0f + erff(val * 0.70710678118654752f));
                if (vreg) SMEM[col * LE + row] = f2bf(val);
                else      SMEM[row * LE + col] = f2bf(val);
            }
        }
    }
    __syncthreads();
    const int rr = t >> 1, half = (t & 1) * 64;
    if (EPI == EPI_RES || EPI == EPI_GELU) {
        const size_t base = (size_t)(m0 + rr) * N + n0 + half;
        const unsigned short* src = SMEM + rr * LE + half;
#pragma unroll
        for (int j = 0; j < 8; j++) {
            float v[8];
            load8(src + j * 8, v);
            if (EPI == EPI_RES) {
                float rv[8];
                load8(res + base + j * 8, rv);
#pragma unroll
                for (int i = 0; i < 8; i++) v[i] += rv[i];
            }
            store8(o0 + base + j * 8, v);
        }
    } else if (!vreg) {  // q/k: out[(bh*2048+s)*64 + d]
        const int gcol0 = n0 + half;
        const int which = gcol0 >> 10;
        const int hn = (gcol0 & 1023) >> 6;
        const int grow = m0 + rr;
        const size_t bh = (size_t)((grow >> 11) * 16 + hn);
        unsigned short* dst = (which == 0) ? (unsigned short*)o0 : o1;
        dst += (bh * 2048 + (grow & 2047)) * 64;
        const unsigned short* src = SMEM + rr * LE + half;
#pragma unroll
        for (int j = 0; j < 8; j++)
            *(short8*)(dst + j * 8) = *(const short8*)(src + j * 8);
    } else {  // v^T: out[(bh*64+d)*2048 + s], staged transposed
        const int c = rr;
        const int rem = (n0 + c) - 2048;
        const int hn = rem >> 6, d = rem & 63;
        const size_t bh = (size_t)((m0 >> 11) * 16 + hn);
        unsigned short* dst = o2 + (bh * 64 + d) * 2048 + (m0 & 2047) + half;
        const unsigned short* src = SMEM + c * LE + half;
#pragma unroll
        for (int j = 0; j < 8; j++)
            *(short8*)(dst + j * 8) = *(const short8*)(src + j * 8);
    }
}

// ---------------- GEMM 256xBN (FFN1/FFN2): r5 counted-vmcnt + spread staging ----
// Change vs r5 (passed, 140us): staging spread per m196 fine-interleave.
//   ph1: STAGE_B(kt+1) -> buf[(kt+1)&1] (its prior-tile B reads completed at
//        end of ph3 of kt-1, two barriers ago).
//   ph4: STAGE_A(kt+2) -> buf[kt&1] (last read of this buffer, READ_A(1),
//        lgkm-completes inside ph3 before its closing barrier).
// FIFO at end-of-ph4 wait: [B(kt+1) x BQ, A(kt+2) x 4] -> vmcnt(4) retires tile
// kt+1 fully while kt+2's A stays in flight. Tail: vmcnt(0) when no A staged.
// Wait sits BEFORE the closing s_barrier so barrier-crossing implies all waves'
// loads landed. No setprio (kept from r5; T5 untouched this round).
template <int BN, int EPI, typename RT, typename OT>
__global__ __launch_bounds__(512, 2) void gemm256(
    const unsigned short* __restrict__ A, const unsigned short* __restrict__ Bt,
    const float* __restrict__ bias, const RT* __restrict__ res,
    OT* __restrict__ o0, unsigned short* __restrict__ o1,
    unsigned short* __restrict__ o2, int M, int N, int K) {
    constexpr int NFRAG = BN / 64;
    constexpr int NF2 = NFRAG / 2;
    constexpr int BQ = BN / 64;         // B staging quarters (4 or 2)
    constexpr int ASZ = 16384;          // A region, shorts (256x64)
    constexpr int BSZ = BN * 64;        // B region, shorts
    constexpr int BUFSH = ASZ + BSZ;
    constexpr int PE = BN + 8;          // epilogue row pitch (shorts)
    __shared__ __align__(16) unsigned short SMEM[2 * BUFSH];
    const int t = threadIdx.x;
    const int wave = t >> 6, lane = t & 63;
    const int lr = lane & 15, lq = lane >> 4;
    const int wm = wave >> 2, wn = wave & 3;
    const int m0 = blockIdx.y * 256, n0 = blockIdx.x * BN;
    const int xr3 = lr & 7;
    f32x4 acc[8][NFRAG] = {};
    short8 a[4][2], b0[NF2][2], b1[NF2][2];
    const int srow = t >> 3;
    const int scol = (((t & 7) ^ ((t >> 3) & 7)) << 3);
    const unsigned short* agS = A + (size_t)(m0 + srow) * K + scol;
    const unsigned short* bgS = Bt + (size_t)(n0 + srow) * K + scol;
    const size_t q64K = (size_t)64 * K;

#define STAGE_A(ktv, dv) do {                                                 \
    unsigned short* dA_ = SMEM + (dv) * BUFSH;                                \
    const int ko_ = (ktv) << 6;                                               \
    _Pragma("unroll") for (int qi = 0; qi < 4; ++qi)                          \
        gload16(agS + (size_t)qi * q64K + ko_, dA_ + qi * 4096 + t * 8);      \
} while (0)

#define STAGE_B(ktv, dv) do {                                                 \
    unsigned short* dB_ = SMEM + (dv) * BUFSH + ASZ;                          \
    const int ko_ = (ktv) << 6;                                               \
    _Pragma("unroll") for (int qi = 0; qi < BQ; ++qi)                         \
        gload16(bgS + (size_t)qi * q64K + ko_, dB_ + qi * 4096 + t * 8);      \
} while (0)

#define READ_A(qm) do {                                                       \
    _Pragma("unroll") for (int mi = 0; mi < 4; ++mi) {                        \
        const int rA_ = wm * 128 + (qm) * 64 + mi * 16 + lr;                  \
        _Pragma("unroll") for (int ks = 0; ks < 2; ++ks)                      \
            a[mi][ks] = *(const short8*)(Ash + rA_ * 64 + (((ks * 4 + lq) ^ xr3) << 3)); \
    } } while (0)

#define READ_B(qn, barr) do {                                                 \
    _Pragma("unroll") for (int ni = 0; ni < NF2; ++ni) {                      \
        const int rB_ = wn * (BN / 4) + (qn) * (BN / 8) + ni * 16 + lr;       \
        _Pragma("unroll") for (int ks = 0; ks < 2; ++ks)                      \
            barr[ni][ks] = *(const short8*)(Bsh + rB_ * 64 + (((ks * 4 + lq) ^ xr3) << 3)); \
    } } while (0)

#define MFMAQ(qm, qn, barr) do {                                              \
    _Pragma("unroll") for (int mi = 0; mi < 4; ++mi)                          \
        _Pragma("unroll") for (int ni = 0; ni < NF2; ++ni) {                  \
            f32x4 c_ = acc[(qm) * 4 + mi][(qn) * NF2 + ni];                   \
            c_ = __builtin_amdgcn_mfma_f32_16x16x32_bf16(a[mi][0], barr[ni][0], c_, 0, 0, 0); \
            c_ = __builtin_amdgcn_mfma_f32_16x16x32_bf16(a[mi][1], barr[ni][1], c_, 0, 0, 0); \
            acc[(qm) * 4 + mi][(qn) * NF2 + ni] = c_;                         \
        } } while (0)

#define BARRIER __builtin_amdgcn_s_barrier()
#define VMW4 asm volatile("s_waitcnt vmcnt(4)" ::: "memory")
#define VMW0 asm volatile("s_waitcnt vmcnt(0)" ::: "memory")

    const int nkt = K >> 6;
    // prologue FIFO: [A(0)x4, B(0)xBQ, A(1)x4]; vmcnt(4) retires tile 0 fully.
    STAGE_A(0, 0);
    STAGE_B(0, 0);
    if (nkt > 1) { STAGE_A(1, 1); VMW4; } else { VMW0; }
    BARRIER;
    for (int kt = 0; kt < nkt; ++kt) {
        const unsigned short* Ash = SMEM + (kt & 1) * BUFSH;
        const unsigned short* Bsh = Ash + ASZ;
        // ph1: reads of tile kt quadrant (0,0); spread-stage B(kt+1)
        READ_A(0);
        READ_B(0, b0);
        if (kt + 1 < nkt) STAGE_B(kt + 1, (kt + 1) & 1);
        BARRIER;
        MFMAQ(0, 0, b0);
        BARRIER;
        // ph2: quadrant (0,1)
        READ_B(1, b1);
        BARRIER;
        MFMAQ(0, 1, b1);
        BARRIER;
        // ph3: quadrant (1,1) — last reads of this tile's buffer
        READ_A(1);
        BARRIER;
        MFMAQ(1, 1, b1);
        BARRIER;
        // ph4: spread-stage A(kt+2) into the just-freed buffer; pure-MFMA (1,0)
        if (kt + 2 < nkt) {
            STAGE_A(kt + 2, kt & 1);
            MFMAQ(1, 0, b0);
            VMW4;           // retires tile kt+1 fully; kt+2's A stays in flight
        } else {
            MFMAQ(1, 0, b0);
            VMW0;           // tail: nothing newer than tile kt+1's loads
        }
        BARRIER;
    }
#undef STAGE_A
#undef STAGE_B
#undef READ_A
#undef READ_B
#undef MFMAQ
#undef BARRIER
#undef VMW4
#undef VMW0

    // ---- epilogue: two row-half passes through LDS -> coalesced writes ----
    __syncthreads();
    const bool vreg = (EPI == EPI_QKV) && (n0 >= 2048);
    for (int h = 0; h < 2; ++h) {
        if (h) __syncthreads();
        if (wm == h) {
#pragma unroll
            for (int nj = 0; nj < NFRAG; ++nj) {
                const int col = wn * (BN / 4) + nj * 16 + lr;
                const float bv = bias[n0 + col];
#pragma unroll
                for (int mi = 0; mi < 8; ++mi) {
#pragma unroll
                    for (int r = 0; r < 4; ++r) {
                        const int lrow = mi * 16 + lq * 4 + r;
                        float val = acc[mi][nj][r] + bv;
                        if (EPI == EPI_GELU)
                            val = 0.5f * val * (1.0f + erff(val * 0.70710678118654752f));
                        if (vreg) SMEM[col * 136 + lrow] = f2bf(val);
                        else      SMEM[lrow * PE + col] = f2bf(val);
                    }
                }
            }
        }
        __syncthreads();
        if (EPI == EPI_RES || EPI == EPI_GELU) {
            const int rr = t >> 2, sg = (t & 3) * (BN / 4);
            const size_t base = (size_t)(m0 + h * 128 + rr) * N + n0 + sg;
            const unsigned short* src = SMEM + rr * PE + sg;
#pragma unroll
            for (int j = 0; j < BN / 32; ++j) {
                float v[8];
                load8(src + j * 8, v);
                if (EPI == EPI_RES) {
                    float rv[8];
                    load8(res + base + j * 8, rv);
#pragma unroll
                    for (int i = 0; i < 8; i++) v[i] += rv[i];
                }
                store8(o0 + base + j * 8, v);
            }
        }
    }
}

// ---------------- Flash attention (r9 exact, measured 126us) ----------------
// 256-row Q-tile, 8 waves x 32 rows, paired (q,7-q) -> 256 uniform blocks.
__global__ __launch_bounds__(512) void attn_kernel(
    const unsigned short* __restrict__ qb, const unsigned short* __restrict__ kb,
    const unsigned short* __restrict__ vtb, unsigned short* __restrict__ aout) {
    const int bx = blockIdx.x;  // 0..3
    const int bh = blockIdx.y;
    const int bidx = bh >> 4, h = bh & 15;
    const int t = threadIdx.x, wave = t >> 6, lane = t & 63;
    const int lr = lane & 15, lq = lane >> 4;
    __shared__ __align__(16) unsigned short Ks[64 * 68];
    __shared__ __align__(16) unsigned short Vs[64 * 68];
    __shared__ __align__(16) unsigned short Ps[8][32 * 68];
    const unsigned short* kbase = kb + (size_t)bh * 2048 * 64;
    const unsigned short* vbase = vtb + (size_t)bh * 64 * 2048;
    const int srow = t >> 3, scol = (t & 7) * 8;
    const float kQScale = 0.125f * 1.44269504088896f;

    for (int phase = 0; phase < 2; phase++) {
        const int qblk = phase ? (7 - bx) : bx;
        const unsigned short* qbase = qb + ((size_t)bh * 2048 + qblk * 256 + wave * 32) * 64;
        short8 qf[2][2];
#pragma unroll
        for (int f = 0; f < 2; f++)
#pragma unroll
            for (int c = 0; c < 2; c++) {
                short8 raw = *(const short8*)(qbase + (f * 16 + lr) * 64 + c * 32 + lq * 8);
                short8 sc;
#pragma unroll
                for (int j = 0; j < 8; j++)
                    sc[j] = (short)f2bf(bf2f((unsigned short)raw[j]) * kQScale);
                qf[f][c] = sc;
            }
        f32x4 acc[2][4] = {};
        float m_i[2][4], l_i[2][4];
#pragma unroll
        for (int f = 0; f < 2; f++)
#pragma unroll
            for (int r = 0; r < 4; r++) { m_i[f][r] = -1e30f; l_i[f][r] = 0.0f; }
        const int wave_q0 = qblk * 256 + wave * 32;
        const int nkt = 4 * (qblk + 1);
        short8 kr = *(const short8*)(kbase + t * 8);
        short8 vr = *(const short8*)(vbase + (size_t)srow * 2048 + scol);
        for (int kt = 0; kt < nkt; kt++) {
            __syncthreads();
            *(short8*)(Ks + srow * 68 + scol) = kr;
            *(short8*)(Vs + srow * 68 + scol) = vr;
            __syncthreads();
            if (kt + 1 < nkt) {
                kr = *(const short8*)(kbase + (size_t)(kt + 1) * 4096 + t * 8);
                vr = *(const short8*)(vbase + (size_t)srow * 2048 + (kt + 1) * 64 + scol);
            }
            if (kt * 64 <= wave_q0 + 31) {
                f32x4 sa[2][4];
#pragma unroll
                for (int ni = 0; ni < 4; ni++) {
                    short8 kf0 = *(const short8*)(Ks + (ni * 16 + lr) * 68 + lq * 8);
                    short8 kf1 = *(const short8*)(Ks + (ni * 16 + lr) * 68 + 32 + lq * 8);
#pragma unroll
                    for (int f = 0; f < 2; f++) {
                        f32x4 z = {};
                        z = __builtin_amdgcn_mfma_f32_16x16x32_bf16(qf[f][0], kf0, z, 0, 0, 0);
                        sa[f][ni] = __builtin_amdgcn_mfma_f32_16x16x32_bf16(qf[f][1], kf1, z, 0, 0, 0);
                    }
                }
                const bool needmask = (kt * 64 + 63 > wave_q0);
                if (needmask) {
#pragma unroll
                    for (int f = 0; f < 2; f++) {
                        const int qrow0 = wave_q0 + f * 16 + lq * 4;
#pragma unroll
                        for (int ni = 0; ni < 4; ni++) {
                            const int kcol = kt * 64 + ni * 16 + lr;
#pragma unroll
                            for (int r = 0; r < 4; r++)
                                if (kcol > qrow0 + r) sa[f][ni][r] = -1e30f;
                        }
                    }
                }
#pragma unroll
                for (int f = 0; f < 2; f++) {
                    float mcur[4], alpha[4], rsum[4];
#pragma unroll
                    for (int r = 0; r < 4; r++)
                        mcur[r] = fmaxf(fmaxf(sa[f][0][r], sa[f][1][r]), fmaxf(sa[f][2][r], sa[f][3][r]));
#pragma unroll
                    for (int r = 0; r < 4; r++) {
#pragma unroll
                        for (int off = 1; off < 16; off <<= 1) mcur[r] = fmaxf(mcur[r], __shfl_xor(mcur[r], off));
                        const float mn = fmaxf(m_i[f][r], mcur[r]);
                        alpha[r] = fexp2(m_i[f][r] - mn);
                        m_i[f][r] = mn;
                        rsum[r] = 0.0f;
                    }
#pragma unroll
                    for (int ni = 0; ni < 4; ni++)
#pragma unroll
                        for (int r = 0; r < 4; r++) {
                            const float p = fexp2(sa[f][ni][r] - m_i[f][r]);
                            Ps[wave][(f * 16 + lq * 4 + r) * 68 + ni * 16 + lr] = f2bf(p);
                            rsum[r] += p;
                        }
#pragma unroll
                    for (int r = 0; r < 4; r++) {
#pragma unroll
                        for (int off = 1; off < 16; off <<= 1) rsum[r] += __shfl_xor(rsum[r], off);
                        l_i[f][r] = l_i[f][r] * alpha[r] + rsum[r];
#pragma unroll
                        for (int ni = 0; ni < 4; ni++) acc[f][ni][r] *= alpha[r];
                    }
                }
                short8 pf[2][2];
#pragma unroll
                for (int f = 0; f < 2; f++)
#pragma unroll
                    for (int c = 0; c < 2; c++)
                        pf[f][c] = *(const short8*)(&Ps[wave][(f * 16 + lr) * 68 + c * 32 + lq * 8]);
#pragma unroll
                for (int ni = 0; ni < 4; ni++) {
                    short8 vf0 = *(const short8*)(Vs + (ni * 16 + lr) * 68 + lq * 8);
                    short8 vf1 = *(const short8*)(Vs + (ni * 16 + lr) * 68 + 32 + lq * 8);
#pragma unroll
                    for (int f = 0; f < 2; f++) {
                        acc[f][ni] = __builtin_amdgcn_mfma_f32_16x16x32_bf16(pf[f][0], vf0, acc[f][ni], 0, 0, 0);
                        acc[f][ni] = __builtin_amdgcn_mfma_f32_16x16x32_bf16(pf[f][1], vf1, acc[f][ni], 0, 0, 0);
                    }
                }
            }
        }
#pragma unroll
        for (int f = 0; f < 2; f++)
#pragma unroll
            for (int r = 0; r < 4; r++) {
                const float rinv = 1.0f / l_i[f][r];
                const int q = qblk * 256 + wave * 32 + f * 16 + lq * 4 + r;
                const size_t token = (size_t)bidx * 2048 + q;
#pragma unroll
                for (int ni = 0; ni < 4; ni++)
                    aout[token * 1024 + h * 64 + ni * 16 + lr] = f2bf(acc[f][ni][r] * rinv);
            }
    }
}

// ---------------- launch ----------------
extern "C" void kernel_launch(void* const* d_in, const int* in_sizes, int n_in,
                              void* d_out, int out_size, void* d_ws, size_t ws_size,
                              hipStream_t stream) {
    const float* x      = (const float*)d_in[0];
    const float* qkv_w  = (const float*)d_in[1];
    const float* qkv_b  = (const float*)d_in[2];
    const float* out_w  = (const float*)d_in[3];
    const float* out_b  = (const float*)d_in[4];
    const float* ffn1_w = (const float*)d_in[5];
    const float* ffn1_b = (const float*)d_in[6];
    const float* ffn2_w = (const float*)d_in[7];
    const float* ffn2_b = (const float*)d_in[8];
    const float* ln1_g  = (const float*)d_in[9];
    const float* ln1_b  = (const float*)d_in[10];
    const float* ln2_g  = (const float*)d_in[11];
    const float* ln2_b  = (const float*)d_in[12];
    float* out = (float*)d_out;
    char* W = (char*)d_ws;

    unsigned short* normed = (unsigned short*)(W);
    unsigned short* x1     = (unsigned short*)(W + 16777216);
    unsigned short* qbuf   = (unsigned short*)(W + 33554432);
    unsigned short* kbuf   = (unsigned short*)(W + 50331648);
    unsigned short* vbuf   = (unsigned short*)(W + 67108864);
    unsigned short* attnb  = (unsigned short*)(W + 83886080);
    unsigned short* hff    = (unsigned short*)(W + 33554432);  // reuses q/k/v/attn (dead)
    unsigned short* qkv_wt = (unsigned short*)(W + 100663296);
    unsigned short* out_wt = (unsigned short*)(W + 106954752);
    unsigned short* f1_wt  = (unsigned short*)(W + 109051904);
    unsigned short* f2_wt  = (unsigned short*)(W + 117440512);

    transpose_cast_kernel<<<dim3(3072 / 32, 1024 / 32), 256, 0, stream>>>(qkv_w, qkv_wt, 1024, 3072);
    transpose_cast_kernel<<<dim3(1024 / 32, 1024 / 32), 256, 0, stream>>>(out_w, out_wt, 1024, 1024);
    transpose_cast_kernel<<<dim3(4096 / 32, 1024 / 32), 256, 0, stream>>>(ffn1_w, f1_wt, 1024, 4096);
    transpose_cast_kernel<<<dim3(1024 / 32, 4096 / 32), 256, 0, stream>>>(ffn2_w, f2_wt, 4096, 1024);

    ln_f32_kernel<<<dim3(8192), 256, 0, stream>>>(x, ln1_g, ln1_b, normed);
    gemm_bt<EPI_QKV, float, unsigned short><<<dim3(3072 / 128, 8192 / 128), 256, 0, stream>>>(
        normed, qkv_wt, qkv_b, nullptr, qbuf, kbuf, vbuf, 8192, 3072, 1024);
    attn_kernel<<<dim3(4, 64), 512, 0, stream>>>(qbuf, kbuf, vbuf, attnb);
    gemm_bt<EPI_RES, float, unsigned short><<<dim3(1024 / 128, 8192 / 128), 256, 0, stream>>>(
        attnb, out_wt, out_b, x, x1, nullptr, nullptr, 8192, 1024, 1024);
    ln_bf16_kernel<<<dim3(8192), 256, 0, stream>>>(x1, ln2_g, ln2_b, normed);
    gemm256<256, EPI_GELU, float, unsigned short><<<dim3(4096 / 256, 8192 / 256), 512, 0, stream>>>(
        normed, f1_wt, ffn1_b, nullptr, hff, nullptr, nullptr, 8192, 4096, 1024);
    gemm256<128, EPI_RES, unsigned short, float><<<dim3(1024 / 128, 8192 / 256), 512, 0, stream>>>(
        hff, f2_wt, ffn2_b, x1, out, nullptr, nullptr, 8192, 1024, 4096);
}

// Round 12
// 597.499 us; speedup vs baseline: 1.1590x; 1.0013x over previous
//
#include <hip/hip_runtime.h>
#include <hip/hip_bf16.h>
#include <math.h>

typedef __attribute__((ext_vector_type(8))) short short8;
typedef __attribute__((ext_vector_type(4))) float f32x4;

__device__ __forceinline__ float bf2f(unsigned short u) {
    union { unsigned int i; float f; } c; c.i = ((unsigned int)u) << 16; return c.f;
}
__device__ __forceinline__ unsigned short f2bf(float f) {
    union { float f; unsigned int i; } c; c.f = f;
    unsigned int i = c.i;
    unsigned int r = (i + 0x7FFFu + ((i >> 16) & 1u)) >> 16;
    return (unsigned short)r;
}
__device__ __forceinline__ float fexp2(float x) { return __builtin_amdgcn_exp2f(x); }

// vectorized 8-wide helpers for epilogue readback
__device__ __forceinline__ void load8(const unsigned short* p, float* v) {
    short8 s = *(const short8*)p;
#pragma unroll
    for (int i = 0; i < 8; i++) v[i] = bf2f((unsigned short)s[i]);
}
__device__ __forceinline__ void load8(const float* p, float* v) {
    f32x4 a = ((const f32x4*)p)[0], b = ((const f32x4*)p)[1];
    v[0] = a[0]; v[1] = a[1]; v[2] = a[2]; v[3] = a[3];
    v[4] = b[0]; v[5] = b[1]; v[6] = b[2]; v[7] = b[3];
}
__device__ __forceinline__ void store8(unsigned short* p, const float* v) {
    short8 s;
#pragma unroll
    for (int i = 0; i < 8; i++) s[i] = (short)f2bf(v[i]);
    *(short8*)p = s;
}
__device__ __forceinline__ void store8(float* p, const float* v) {
    f32x4 a, b;
    a[0] = v[0]; a[1] = v[1]; a[2] = v[2]; a[3] = v[3];
    b[0] = v[4]; b[1] = v[5]; b[2] = v[6]; b[3] = v[7];
    ((f32x4*)p)[0] = a; ((f32x4*)p)[1] = b;
}

// ---------------- LayerNorm (fp32 input) -> bf16 output ----------------
__global__ __launch_bounds__(256) void ln_f32_kernel(
    const float* __restrict__ x, const float* __restrict__ g,
    const float* __restrict__ b, unsigned short* __restrict__ out) {
    const int row = blockIdx.x;
    const int t = threadIdx.x;
    const float* xr = x + (size_t)row * 1024;
    float4 raw = ((const float4*)xr)[t];
    float v0 = raw.x, v1 = raw.y, v2 = raw.z, v3 = raw.w;
    float s = v0 + v1 + v2 + v3;
    float ss = v0 * v0 + v1 * v1 + v2 * v2 + v3 * v3;
    for (int off = 32; off > 0; off >>= 1) {
        s += __shfl_down(s, off);
        ss += __shfl_down(ss, off);
    }
    __shared__ float red[8];
    __shared__ float stat[2];
    const int wave = t >> 6, lane = t & 63;
    if (lane == 0) { red[wave] = s; red[4 + wave] = ss; }
    __syncthreads();
    if (t == 0) {
        float st = red[0] + red[1] + red[2] + red[3];
        float sst = red[4] + red[5] + red[6] + red[7];
        float mu = st * (1.0f / 1024.0f);
        float var = sst * (1.0f / 1024.0f) - mu * mu;
        stat[0] = mu; stat[1] = rsqrtf(var + 1e-5f);
    }
    __syncthreads();
    const float mu = stat[0], rstd = stat[1];
    float4 gr = ((const float4*)g)[t];
    float4 br = ((const float4*)b)[t];
    ushort4 o;
    o.x = f2bf((v0 - mu) * rstd * gr.x + br.x);
    o.y = f2bf((v1 - mu) * rstd * gr.y + br.y);
    o.z = f2bf((v2 - mu) * rstd * gr.z + br.z);
    o.w = f2bf((v3 - mu) * rstd * gr.w + br.w);
    ((ushort4*)(out + (size_t)row * 1024))[t] = o;
}

// ---------------- LayerNorm (bf16 input) -> bf16 output ----------------
__global__ __launch_bounds__(256) void ln_bf16_kernel(
    const unsigned short* __restrict__ x, const float* __restrict__ g,
    const float* __restrict__ b, unsigned short* __restrict__ out) {
    const int row = blockIdx.x;
    const int t = threadIdx.x;
    const unsigned short* xr = x + (size_t)row * 1024;
    ushort4 raw = ((const ushort4*)xr)[t];
    float v0 = bf2f(raw.x), v1 = bf2f(raw.y), v2 = bf2f(raw.z), v3 = bf2f(raw.w);
    float s = v0 + v1 + v2 + v3;
    float ss = v0 * v0 + v1 * v1 + v2 * v2 + v3 * v3;
    for (int off = 32; off > 0; off >>= 1) {
        s += __shfl_down(s, off);
        ss += __shfl_down(ss, off);
    }
    __shared__ float red[8];
    __shared__ float stat[2];
    const int wave = t >> 6, lane = t & 63;
    if (lane == 0) { red[wave] = s; red[4 + wave] = ss; }
    __syncthreads();
    if (t == 0) {
        float st = red[0] + red[1] + red[2] + red[3];
        float sst = red[4] + red[5] + red[6] + red[7];
        float mu = st * (1.0f / 1024.0f);
        float var = sst * (1.0f / 1024.0f) - mu * mu;
        stat[0] = mu; stat[1] = rsqrtf(var + 1e-5f);
    }
    __syncthreads();
    const float mu = stat[0], rstd = stat[1];
    float4 gr = ((const float4*)g)[t];
    float4 br = ((const float4*)b)[t];
    ushort4 o;
    o.x = f2bf((v0 - mu) * rstd * gr.x + br.x);
    o.y = f2bf((v1 - mu) * rstd * gr.y + br.y);
    o.z = f2bf((v2 - mu) * rstd * gr.z + br.z);
    o.w = f2bf((v3 - mu) * rstd * gr.w + br.w);
    ((ushort4*)(out + (size_t)row * 1024))[t] = o;
}

// ---------------- Transpose+cast: fp32 in[R][C] -> bf16 out[C][R] ----------------
__global__ __launch_bounds__(256) void transpose_cast_kernel(
    const float* __restrict__ in, unsigned short* __restrict__ out, int R, int C) {
    __shared__ unsigned short tile[32][33];
    const int bx = blockIdx.x * 32, by = blockIdx.y * 32;
    const int tx = threadIdx.x & 31, ty = threadIdx.x >> 5;
    for (int i = 0; i < 32; i += 8)
        tile[ty + i][tx] = f2bf(in[(size_t)(by + ty + i) * C + bx + tx]);
    __syncthreads();
    for (int i = 0; i < 32; i += 8)
        out[(size_t)(bx + ty + i) * R + by + tx] = tile[tx][ty + i];
}

// ---------------- GEMM (r0): 128x128 tile, reg-staged — ALL four GEMMs --------
// r11 evidence: gemm_bt FFN dispatches all < 126us (beat every 256^2 variant).
enum { EPI_QKV = 0, EPI_RES = 1, EPI_GELU = 2 };

template <int EPI, typename RT, typename OT>
__global__ __launch_bounds__(256) void gemm_bt(
    const unsigned short* __restrict__ A, const unsigned short* __restrict__ Bt,
    const float* __restrict__ bias, const RT* __restrict__ res,
    OT* __restrict__ o0, unsigned short* __restrict__ o1,
    unsigned short* __restrict__ o2, int M, int N, int K) {
    constexpr int LDW = 40;   // staging row pitch (shorts)
    constexpr int LE = 136;   // epilogue row pitch (shorts)
    __shared__ __align__(16) unsigned short SMEM[20480];  // 40 KB
    const int t = threadIdx.x;
    const int wave = t >> 6, lane = t & 63;
    const int lr = lane & 15, lq = lane >> 4;
    const int wm = (wave >> 1) * 64, wn = (wave & 1) * 64;
    const int m0 = blockIdx.y * 128, n0 = blockIdx.x * 128;
    f32x4 acc[4][4] = {};
    const int arow = t >> 2, acol = (t & 3) << 3;
    const unsigned short* ag = A + (size_t)(m0 + arow) * K + acol;
    const unsigned short* bg = Bt + (size_t)(n0 + arow) * K + acol;
    const size_t rstride = (size_t)64 * K;
    short8 a0 = *(const short8*)(ag);
    short8 a1 = *(const short8*)(ag + rstride);
    short8 b0 = *(const short8*)(bg);
    short8 b1 = *(const short8*)(bg + rstride);
    const int nit = K >> 5;
    for (int it = 0; it < nit; ++it) {
        const int buf = (it & 1) * 10240;
        unsigned short* As = SMEM + buf;
        unsigned short* Bs = SMEM + buf + 5120;
        *(short8*)(As + arow * LDW + acol) = a0;
        *(short8*)(As + (arow + 64) * LDW + acol) = a1;
        *(short8*)(Bs + arow * LDW + acol) = b0;
        *(short8*)(Bs + (arow + 64) * LDW + acol) = b1;
        if (it + 1 < nit) {
            const int k0 = (it + 1) << 5;
            a0 = *(const short8*)(ag + k0);
            a1 = *(const short8*)(ag + rstride + k0);
            b0 = *(const short8*)(bg + k0);
            b1 = *(const short8*)(bg + rstride + k0);
        }
        __syncthreads();
        short8 af[4], bfr[4];
#pragma unroll
        for (int i = 0; i < 4; i++) af[i] = *(const short8*)(As + (wm + i * 16 + lr) * LDW + lq * 8);
#pragma unroll
        for (int i = 0; i < 4; i++) bfr[i] = *(const short8*)(Bs + (wn + i * 16 + lr) * LDW + lq * 8);
#pragma unroll
        for (int mi = 0; mi < 4; mi++)
#pragma unroll
            for (int ni = 0; ni < 4; ni++)
                acc[mi][ni] = __builtin_amdgcn_mfma_f32_16x16x32_bf16(af[mi], bfr[ni], acc[mi][ni], 0, 0, 0);
    }
    __syncthreads();
    const bool vreg = (EPI == EPI_QKV) && (n0 >= 2048);
#pragma unroll
    for (int ni = 0; ni < 4; ni++) {
        const int col = wn + ni * 16 + lr;
        const float bv = bias[n0 + col];
#pragma unroll
        for (int mi = 0; mi < 4; mi++) {
#pragma unroll
            for (int r = 0; r < 4; r++) {
                const int row = wm + mi * 16 + lq * 4 + r;
                float val = acc[mi][ni][r] + bv;
                if (EPI == EPI_GELU)
                    val = 0.5f * val * (1.0f + erff(val * 0.70710678118654752f));
                if (vreg) SMEM[col * LE + row] = f2bf(val);
                else      SMEM[row * LE + col] = f2bf(val);
            }
        }
    }
    __syncthreads();
    const int rr = t >> 1, half = (t & 1) * 64;
    if (EPI == EPI_RES || EPI == EPI_GELU) {
        const size_t base = (size_t)(m0 + rr) * N + n0 + half;
        const unsigned short* src = SMEM + rr * LE + half;
#pragma unroll
        for (int j = 0; j < 8; j++) {
            float v[8];
            load8(src + j * 8, v);
            if (EPI == EPI_RES) {
                float rv[8];
                load8(res + base + j * 8, rv);
#pragma unroll
                for (int i = 0; i < 8; i++) v[i] += rv[i];
            }
            store8(o0 + base + j * 8, v);
        }
    } else if (!vreg) {  // q/k: out[(bh*2048+s)*64 + d]
        const int gcol0 = n0 + half;
        const int which = gcol0 >> 10;
        const int hn = (gcol0 & 1023) >> 6;
        const int grow = m0 + rr;
        const size_t bh = (size_t)((grow >> 11) * 16 + hn);
        unsigned short* dst = (which == 0) ? (unsigned short*)o0 : o1;
        dst += (bh * 2048 + (grow & 2047)) * 64;
        const unsigned short* src = SMEM + rr * LE + half;
#pragma unroll
        for (int j = 0; j < 8; j++)
            *(short8*)(dst + j * 8) = *(const short8*)(src + j * 8);
    } else {  // v^T: out[(bh*64+d)*2048 + s], staged transposed
        const int c = rr;
        const int rem = (n0 + c) - 2048;
        const int hn = rem >> 6, d = rem & 63;
        const size_t bh = (size_t)((m0 >> 11) * 16 + hn);
        unsigned short* dst = o2 + (bh * 64 + d) * 2048 + (m0 & 2047) + half;
        const unsigned short* src = SMEM + c * LE + half;
#pragma unroll
        for (int j = 0; j < 8; j++)
            *(short8*)(dst + j * 8) = *(const short8*)(src + j * 8);
    }
}

// ---------------- Flash attention v3, causal. Hd=64, S=2048, BH=64 ----------------
// r12: TLP doubling. r9 counters (MfmaUtil 11.6 / VALUBusy 40 / HBM 10 / Occ 22)
// show latency-bound with the GRID as the occupancy cap (1 block/CU). Now:
// 128-row Q-tiles on 512-thread blocks (8 waves x 16 rows — r8's verified
// per-wave code), paired (bx, 15-bx) -> grid 8x64 = 512 UNIFORM blocks
// (34 staging units each) = 2 blocks/CU = 16 waves/CU. LDS 34.8KB/block
// (2x fits), VGPR ~64. Two independent blocks per CU overlap each other's
// barrier/VALU stalls. No setprio (r10 lesson: negative in lockstep blocks).
__global__ __launch_bounds__(512) void attn_kernel(
    const unsigned short* __restrict__ qb, const unsigned short* __restrict__ kb,
    const unsigned short* __restrict__ vtb, unsigned short* __restrict__ aout) {
    const int bx = blockIdx.x;  // 0..7
    const int bh = blockIdx.y;
    const int bidx = bh >> 4, h = bh & 15;
    const int t = threadIdx.x, wave = t >> 6, lane = t & 63;
    const int lr = lane & 15, lq = lane >> 4;
    __shared__ __align__(16) unsigned short Ks[64 * 68];
    __shared__ __align__(16) unsigned short Vs[64 * 68];
    __shared__ __align__(16) unsigned short Ps[8][16 * 68];
    const unsigned short* kbase = kb + (size_t)bh * 2048 * 64;
    const unsigned short* vbase = vtb + (size_t)bh * 64 * 2048;
    const int srow = t >> 3, scol = (t & 7) * 8;  // 512 threads -> rows 0..63
    const float kQScale = 0.125f * 1.44269504088896f;

    for (int phase = 0; phase < 2; phase++) {
        const int qblk = phase ? (15 - bx) : bx;
        const unsigned short* qbase = qb + ((size_t)bh * 2048 + qblk * 128 + wave * 16) * 64;
        short8 qf[2];
#pragma unroll
        for (int c = 0; c < 2; c++) {
            short8 raw = *(const short8*)(qbase + lr * 64 + c * 32 + lq * 8);
            short8 sc;
#pragma unroll
            for (int j = 0; j < 8; j++)
                sc[j] = (short)f2bf(bf2f((unsigned short)raw[j]) * kQScale);
            qf[c] = sc;
        }
        f32x4 acc[4] = {};
        float m_i[4], l_i[4];
#pragma unroll
        for (int r = 0; r < 4; r++) { m_i[r] = -1e30f; l_i[r] = 0.0f; }
        const int wave_q0 = qblk * 128 + wave * 16;
        const int nkt = 2 * (qblk + 1);
        short8 kr = *(const short8*)(kbase + t * 8);
        short8 vr = *(const short8*)(vbase + (size_t)srow * 2048 + scol);
        for (int kt = 0; kt < nkt; kt++) {
            __syncthreads();
            *(short8*)(Ks + srow * 68 + scol) = kr;
            *(short8*)(Vs + srow * 68 + scol) = vr;
            __syncthreads();
            if (kt + 1 < nkt) {
                kr = *(const short8*)(kbase + (size_t)(kt + 1) * 4096 + t * 8);
                vr = *(const short8*)(vbase + (size_t)srow * 2048 + (kt + 1) * 64 + scol);
            }
            // wave processes rows [wave_q0, wave_q0+15]; skip fully-masked tiles
            if (kt * 64 <= wave_q0 + 15) {
                f32x4 sa[4];
#pragma unroll
                for (int ni = 0; ni < 4; ni++) {
                    short8 kf0 = *(const short8*)(Ks + (ni * 16 + lr) * 68 + lq * 8);
                    short8 kf1 = *(const short8*)(Ks + (ni * 16 + lr) * 68 + 32 + lq * 8);
                    f32x4 z = {};
                    z = __builtin_amdgcn_mfma_f32_16x16x32_bf16(qf[0], kf0, z, 0, 0, 0);
                    sa[ni] = __builtin_amdgcn_mfma_f32_16x16x32_bf16(qf[1], kf1, z, 0, 0, 0);
                }
                const bool needmask = (kt * 64 + 63 > wave_q0);
                if (needmask) {
                    const int qrow0 = wave_q0 + lq * 4;
#pragma unroll
                    for (int ni = 0; ni < 4; ni++) {
                        const int kcol = kt * 64 + ni * 16 + lr;
#pragma unroll
                        for (int r = 0; r < 4; r++)
                            if (kcol > qrow0 + r) sa[ni][r] = -1e30f;
                    }
                }
                float mcur[4], alpha[4], rsum[4];
#pragma unroll
                for (int r = 0; r < 4; r++)
                    mcur[r] = fmaxf(fmaxf(sa[0][r], sa[1][r]), fmaxf(sa[2][r], sa[3][r]));
#pragma unroll
                for (int r = 0; r < 4; r++) {
#pragma unroll
                    for (int off = 1; off < 16; off <<= 1) mcur[r] = fmaxf(mcur[r], __shfl_xor(mcur[r], off));
                    const float mn = fmaxf(m_i[r], mcur[r]);
                    alpha[r] = fexp2(m_i[r] - mn);
                    m_i[r] = mn;
                    rsum[r] = 0.0f;
                }
#pragma unroll
                for (int ni = 0; ni < 4; ni++)
#pragma unroll
                    for (int r = 0; r < 4; r++) {
                        const float p = fexp2(sa[ni][r] - m_i[r]);
                        Ps[wave][(lq * 4 + r) * 68 + ni * 16 + lr] = f2bf(p);
                        rsum[r] += p;
                    }
#pragma unroll
                for (int r = 0; r < 4; r++) {
#pragma unroll
                    for (int off = 1; off < 16; off <<= 1) rsum[r] += __shfl_xor(rsum[r], off);
                    l_i[r] = l_i[r] * alpha[r] + rsum[r];
#pragma unroll
                    for (int ni = 0; ni < 4; ni++) acc[ni][r] *= alpha[r];
                }
                short8 pf[2];
#pragma unroll
                for (int c = 0; c < 2; c++)
                    pf[c] = *(const short8*)(&Ps[wave][lr * 68 + c * 32 + lq * 8]);
#pragma unroll
                for (int ni = 0; ni < 4; ni++) {
                    short8 vf0 = *(const short8*)(Vs + (ni * 16 + lr) * 68 + lq * 8);
                    short8 vf1 = *(const short8*)(Vs + (ni * 16 + lr) * 68 + 32 + lq * 8);
                    acc[ni] = __builtin_amdgcn_mfma_f32_16x16x32_bf16(pf[0], vf0, acc[ni], 0, 0, 0);
                    acc[ni] = __builtin_amdgcn_mfma_f32_16x16x32_bf16(pf[1], vf1, acc[ni], 0, 0, 0);
                }
            }
        }
#pragma unroll
        for (int r = 0; r < 4; r++) {
            const float rinv = 1.0f / l_i[r];
            const int q = qblk * 128 + wave * 16 + lq * 4 + r;
            const size_t token = (size_t)bidx * 2048 + q;
#pragma unroll
            for (int ni = 0; ni < 4; ni++)
                aout[token * 1024 + h * 64 + ni * 16 + lr] = f2bf(acc[ni][r] * rinv);
        }
    }
}

// ---------------- launch ----------------
extern "C" void kernel_launch(void* const* d_in, const int* in_sizes, int n_in,
                              void* d_out, int out_size, void* d_ws, size_t ws_size,
                              hipStream_t stream) {
    const float* x      = (const float*)d_in[0];
    const float* qkv_w  = (const float*)d_in[1];
    const float* qkv_b  = (const float*)d_in[2];
    const float* out_w  = (const float*)d_in[3];
    const float* out_b  = (const float*)d_in[4];
    const float* ffn1_w = (const float*)d_in[5];
    const float* ffn1_b = (const float*)d_in[6];
    const float* ffn2_w = (const float*)d_in[7];
    const float* ffn2_b = (const float*)d_in[8];
    const float* ln1_g  = (const float*)d_in[9];
    const float* ln1_b  = (const float*)d_in[10];
    const float* ln2_g  = (const float*)d_in[11];
    const float* ln2_b  = (const float*)d_in[12];
    float* out = (float*)d_out;
    char* W = (char*)d_ws;

    unsigned short* normed = (unsigned short*)(W);
    unsigned short* x1     = (unsigned short*)(W + 16777216);
    unsigned short* qbuf   = (unsigned short*)(W + 33554432);
    unsigned short* kbuf   = (unsigned short*)(W + 50331648);
    unsigned short* vbuf   = (unsigned short*)(W + 67108864);
    unsigned short* attnb  = (unsigned short*)(W + 83886080);
    unsigned short* hff    = (unsigned short*)(W + 33554432);  // reuses q/k/v/attn (dead)
    unsigned short* qkv_wt = (unsigned short*)(W + 100663296);
    unsigned short* out_wt = (unsigned short*)(W + 106954752);
    unsigned short* f1_wt  = (unsigned short*)(W + 109051904);
    unsigned short* f2_wt  = (unsigned short*)(W + 117440512);

    transpose_cast_kernel<<<dim3(3072 / 32, 1024 / 32), 256, 0, stream>>>(qkv_w, qkv_wt, 1024, 3072);
    transpose_cast_kernel<<<dim3(1024 / 32, 1024 / 32), 256, 0, stream>>>(out_w, out_wt, 1024, 1024);
    transpose_cast_kernel<<<dim3(4096 / 32, 1024 / 32), 256, 0, stream>>>(ffn1_w, f1_wt, 1024, 4096);
    transpose_cast_kernel<<<dim3(1024 / 32, 4096 / 32), 256, 0, stream>>>(ffn2_w, f2_wt, 4096, 1024);

    ln_f32_kernel<<<dim3(8192), 256, 0, stream>>>(x, ln1_g, ln1_b, normed);
    gemm_bt<EPI_QKV, float, unsigned short><<<dim3(3072 / 128, 8192 / 128), 256, 0, stream>>>(
        normed, qkv_wt, qkv_b, nullptr, qbuf, kbuf, vbuf, 8192, 3072, 1024);
    attn_kernel<<<dim3(8, 64), 512, 0, stream>>>(qbuf, kbuf, vbuf, attnb);
    gemm_bt<EPI_RES, float, unsigned short><<<dim3(1024 / 128, 8192 / 128), 256, 0, stream>>>(
        attnb, out_wt, out_b, x, x1, nullptr, nullptr, 8192, 1024, 1024);
    ln_bf16_kernel<<<dim3(8192), 256, 0, stream>>>(x1, ln2_g, ln2_b, normed);
    gemm_bt<EPI_GELU, float, unsigned short><<<dim3(4096 / 128, 8192 / 128), 256, 0, stream>>>(
        normed, f1_wt, ffn1_b, nullptr, hff, nullptr, nullptr, 8192, 4096, 1024);
    gemm_bt<EPI_RES, unsigned short, float><<<dim3(1024 / 128, 8192 / 128), 256, 0, stream>>>(
        hff, f2_wt, ffn2_b, x1, out, nullptr, nullptr, 8192, 1024, 4096);
}